// Round 6
// baseline (640.380 us; speedup 1.0000x reference)
//
#include <hip/hip_runtime.h>
#include <hip/hip_bf16.h>
#include <stdint.h>

typedef __bf16 bf16_t;
typedef __bf16 bf16x8 __attribute__((ext_vector_type(8)));
typedef __bf16 bf16x4_t __attribute__((ext_vector_type(4)));
typedef float f32x4 __attribute__((ext_vector_type(4)));

#define AS1 __attribute__((address_space(1)))
#define AS3 __attribute__((address_space(3)))

__device__ __forceinline__ void stage16(const bf16_t* g, char* l) {
    __builtin_amdgcn_global_load_lds((const AS1 uint32_t*)g, (AS3 uint32_t*)l, 16, 0, 0);
}

#define BAR()   __builtin_amdgcn_s_barrier()
#define LGKM0() asm volatile("s_waitcnt lgkmcnt(0)" ::: "memory")
#define VMC(N)  asm volatile("s_waitcnt vmcnt(" #N ")" ::: "memory")
#define PRIO(p) __builtin_amdgcn_s_setprio(p)

// ----------------------------------------------------------------------------
// 256x256 READ-AHEAD 8-phase bf16 GEMM: C = A * Bt^T + bias.
// 512 threads = 8 waves (2M x 4N); per-wave 128x64; 2 LDS buffers of BK=64
// (128 KB); st_16x32 swizzle via pre-swizzled global source + XOR'd ds_read.
//
// R5 lesson: {reads; drain; BAR; MFMA} phase-locks ALL waves -> LDS pipe and
// matrix pipe alternate globally (sum ~1100 cyc/phase, MfmaUtil 48%). Fix:
// intra-wave read-ahead. Window p = { BAR; RDS(p+1)->regs[other]; STG;
// MFMA(p) from regs[cur]; [VMC]; LGKM0 }. The ds_reads for p+1 fly WHILE
// MFMA(p) issues -> both pipes busy in every window. Register double-buffer:
// bA[2] (A-quadrant, alternates by window parity), bB[2] (B-frags, alternates
// by K-tile). MFMA(p)'s operands were read in window p-1 (compiler tracks the
// reg dependency); LGKM0 pre-BAR keeps the cross-wave staging protocol:
//  (i)  all reads drained before each BAR -> staging a region >=1 window
//       after its last read is safe;
//  (ii) reads of staged regions follow a {VMC(n) -> BAR} certification.
//
// Steady-state ledger (reads now ONE window early):
//   reads:  W8: RDB8(0,next)+RDA(0,0,next) ; W1-3: RDA(0,1..3) ;
//           W4: RDB8(1)+RDA(1,0) ; W5-7: RDA(1,1..3)
//   stages: W1: buf1-A(this,4) ; W2/W3: buf0-B(next,2+2) ;
//           W5/W6: buf0-A(next,2+2) ; W7/W8: buf1-B(next,2+2)
//   VMC(4)@W3: queue {pW7,pW8,W1,W2,W3}=12 -> retires pW7/pW8/W1 = buf1-B +
//              buf1-A of THIS tile, certified at BAR(W4) before W4's reads.
//   VMC(2)@W7: queue {W2,W3,W5,W6,W7}=10 -> retires next-buf0 B+A, certified
//              at BAR(W8) before W8's reads.
//   Overwrites: each stage is >=1 full barrier after its region's last read
//   drained (checked: buf0-B pW8-read vs W2-stage; buf0-A W3 vs W5; buf1-B
//   W4 vs W7; buf1-A W7 vs next-W1). Epilogue iter: VMC(0)@W3.
// ----------------------------------------------------------------------------
template <typename OutT>
__global__ __launch_bounds__(512, 2) void gemm256(
    const bf16_t* __restrict__ A, int lda,
    const bf16_t* __restrict__ Bt, int ldb,
    const float* __restrict__ bias,
    OutT* __restrict__ C, int ldc,
    int K, int nTilesN)
{
    __shared__ char smem[131072];
    const int tid  = threadIdx.x;
    const int wave = tid >> 6;
    const int lane = tid & 63;
    const int wm = wave >> 2;   // 0..1 -> rows wm*128..+128
    const int wn = wave & 3;    // 0..3 -> cols wn*64..+64

    // XCD-aware bijective swizzle (gridDim.x % 8 == 0 guaranteed by caller)
    const int bid = blockIdx.x;
    const int swz = (bid & 7) * ((int)gridDim.x >> 3) + (bid >> 3);
    const int m0 = (swz / nTilesN) << 8;
    const int n0 = (swz % nTilesN) << 8;

    // Staging source: wave w, inst j covers subtile rg=w*2+j; lane's 16B chunk
    // col = (lane&3)*8, XOR 16 when subtile row (lane>>2) bit 3 set (inverse
    // st_16x32 pre-swizzle on the global source address).
    const int srow = lane >> 2;
    const int scol = ((lane & 3) * 8) ^ ((lane & 32) >> 1);
    const bf16_t* aS0 = A  + (size_t)(m0 + wave * 32 + srow) * lda + scol;
    const bf16_t* aS1 = aS0 + (size_t)16 * lda;
    const bf16_t* bS0 = Bt + (size_t)(n0 + wave * 32 + srow) * ldb + scol;
    const bf16_t* bS1 = bS0 + (size_t)16 * ldb;

    // LDS map: A(b,kk) = b*65536 + kk*16384 ; B(b,kk) = +32768.
#define STAGE_A(b,kk,kb) do { \
    stage16(aS0 + (kb) + (kk)*32, smem + (b)*65536 + (kk)*16384 + wave*2048); \
    stage16(aS1 + (kb) + (kk)*32, smem + (b)*65536 + (kk)*16384 + wave*2048 + 1024); } while(0)
#define STAGE_B(b,kk,kb) do { \
    stage16(bS0 + (kb) + (kk)*32, smem + (b)*65536 + 32768 + (kk)*16384 + wave*2048); \
    stage16(bS1 + (kb) + (kk)*32, smem + (b)*65536 + 32768 + (kk)*16384 + wave*2048 + 1024); } while(0)

    // ds_read: lane l -> row l&15, k-chunk (l>>4)*16B, with st_16x32 XOR.
    const int rdLane = (lane & 15) * 64 + (((lane >> 4) * 16) ^ ((lane & 8) << 2));
    const char* aRdB = smem + rdLane + wm * 8192;           // + mi*1024 + A(b,kk)
    const char* bRdB = smem + 32768 + rdLane + wn * 4096;   // + ni*1024 + base(b,kk)

    f32x4 acc[8][4];
#pragma unroll
    for (int i = 0; i < 8; ++i)
#pragma unroll
        for (int j = 0; j < 4; ++j) acc[i][j] = (f32x4){0.f, 0.f, 0.f, 0.f};
    bf16x8 bA[2][2][2];  // [window-parity][t][kk] A-quadrant double buffer
    bf16x8 bB[2][2][4];  // [K-tile set][kk][ni]   B-frag double buffer

#define RDB8S(b,s) { _Pragma("unroll") \
    for (int kk = 0; kk < 2; ++kk) _Pragma("unroll") \
        for (int ni = 0; ni < 4; ++ni) \
            bB[s][kk][ni] = *(const bf16x8*)(bRdB + (b)*65536 + kk*16384 + ni*1024); }
#define RDAP(b,mp,pa) { _Pragma("unroll") \
    for (int t = 0; t < 2; ++t) _Pragma("unroll") \
        for (int kk = 0; kk < 2; ++kk) \
            bA[pa][t][kk] = *(const bf16x8*)(aRdB + (b)*65536 + kk*16384 + ((mp)*2+t)*1024); }
#define MFP(mp,pa,s) { _Pragma("unroll") \
    for (int t = 0; t < 2; ++t) _Pragma("unroll") \
        for (int ni = 0; ni < 4; ++ni) _Pragma("unroll") \
            for (int kk = 0; kk < 2; ++kk) \
                acc[(mp)*2+t][ni] = __builtin_amdgcn_mfma_f32_16x16x32_bf16(bA[pa][t][kk], bB[s][kk][ni], acc[(mp)*2+t][ni], 0, 0, 0); }
// Window: barrier; issue next reads (into the OTHER reg buffer); issue stages;
// MFMA from current regs (reads fly underneath); counted vmcnt; drain reads.
#define PH(RDS, STG, MFM, WAIT) do { \
    BAR(); RDS; STG; PRIO(1); MFM; PRIO(0); WAIT; LGKM0(); } while(0)

    // Prologue: buf0 A+B @k=0, buf1-B @k=64 (12 loads); drain; barrier;
    // pre-read W1's operands (B set0 + A quadrant 0 -> parity 1); drain.
    STAGE_A(0, 0, 0);  STAGE_A(0, 1, 0);  STAGE_B(0, 0, 0);  STAGE_B(0, 1, 0);
    STAGE_B(1, 0, 64); STAGE_B(1, 1, 64);
    VMC(0);
    BAR();
    RDB8S(0, 0); RDAP(0, 0, 1); LGKM0();

    const int NI = K >> 7;
    for (int it = 0; it < NI - 1; ++it) {
        const int kB  = (it << 7) + 64;    // this iter's buf1 (A deferred)
        const int kN0 = (it << 7) + 128;   // next buf0
        const int kN1 = (it << 7) + 192;   // next buf1
        PH(RDAP(0,1,0),              STAGE_A(1,0,kB); STAGE_A(1,1,kB), MFP(0,1,0), );
        PH(RDAP(0,2,1),              STAGE_B(0,0,kN0),                 MFP(1,0,0), );
        PH(RDAP(0,3,0),              STAGE_B(0,1,kN0),                 MFP(2,1,0), VMC(4));
        PH(RDB8S(1,1); RDAP(1,0,1),  ,                                 MFP(3,0,0), );
        PH(RDAP(1,1,0),              STAGE_A(0,0,kN0),                 MFP(0,1,1), );
        PH(RDAP(1,2,1),              STAGE_A(0,1,kN0),                 MFP(1,0,1), );
        PH(RDAP(1,3,0),              STAGE_B(1,0,kN1),                 MFP(2,1,1), VMC(2));
        PH(RDB8S(0,0); RDAP(0,0,1),  STAGE_B(1,1,kN1),                 MFP(3,0,1), );
    }
    // Epilogue iteration: stage only buf1-A(this); VMC(0)@W3 certifies all.
    {
        const int kB = ((NI - 1) << 7) + 64;
        PH(RDAP(0,1,0),              STAGE_A(1,0,kB); STAGE_A(1,1,kB), MFP(0,1,0), );
        PH(RDAP(0,2,1),              ,                                 MFP(1,0,0), );
        PH(RDAP(0,3,0),              ,                                 MFP(2,1,0), VMC(0));
        PH(RDB8S(1,1); RDAP(1,0,1),  ,                                 MFP(3,0,0), );
        PH(RDAP(1,1,0),              ,                                 MFP(0,1,1), );
        PH(RDAP(1,2,1),              ,                                 MFP(1,0,1), );
        PH(RDAP(1,3,0),              ,                                 MFP(2,1,1), );
        BAR(); PRIO(1); MFP(3,0,1); PRIO(0);   // final window: no reads
    }
    BAR();

    // ---- Epilogue: LDS-staged coalesced C write (two 128-row halves) ----
    // Write-in swizzle: colb ^= quad*16*CSZ; readback applies same XOR.
    {
        const int mrow = lane & 15;
        const int quad = lane >> 4;
        constexpr int CSZ = (int)sizeof(OutT);
        float bias_v[4];
#pragma unroll
        for (int ni = 0; ni < 4; ++ni)
            bias_v[ni] = bias[n0 + wn * 64 + ni * 16 + mrow];
#pragma unroll
        for (int h = 0; h < 2; ++h) {
            if (wm == h) {
#pragma unroll
                for (int ni = 0; ni < 4; ++ni) {
                    const int colb = (wn * 64 + ni * 16 + mrow) * CSZ;
#pragma unroll
                    for (int mi = 0; mi < 8; ++mi)
#pragma unroll
                        for (int r = 0; r < 4; ++r) {
                            const int lrow = mi * 16 + quad * 4 + r;
                            *(OutT*)(smem + lrow * 256 * CSZ + (colb ^ (quad * 16 * CSZ))) =
                                (OutT)(acc[mi][ni][r] + bias_v[ni]);
                        }
                }
            }
            BAR();
            const int ROUNDS = 128 * 256 * CSZ / 8192;
#pragma unroll
            for (int rd = 0; rd < ROUNDS; ++rd) {
                const int flat = rd * 8192 + tid * 16;
                const int lrow = flat / (256 * CSZ);
                const int colb = flat % (256 * CSZ);
                const int q2 = (lrow >> 2) & 3;
                uint4 v = *(const uint4*)(smem + lrow * 256 * CSZ + (colb ^ (q2 * 16 * CSZ)));
                *(uint4*)((char*)C + ((size_t)(m0 + h * 128 + lrow) * ldc + n0) * CSZ + colb) = v;
            }
            BAR();
        }
    }
#undef STAGE_A
#undef STAGE_B
#undef RDB8S
#undef RDAP
#undef MFP
#undef PH
}

// fp32 -> bf16 elementwise, 4 elems/thread.
__global__ __launch_bounds__(256) void f32_to_bf16(const float* __restrict__ src,
                                                   bf16_t* __restrict__ dst, int n4) {
    int i = blockIdx.x * 256 + threadIdx.x;
    if (i >= n4) return;
    float4 v = ((const float4*)src)[i];
    bf16x4_t o;
    o.x = (bf16_t)v.x; o.y = (bf16_t)v.y; o.z = (bf16_t)v.z; o.w = (bf16_t)v.w;
    ((bf16x4_t*)dst)[i] = o;
}

// dst[cols][rows] (bf16) = src[rows][cols]^T (fp32), 64x64 LDS tiles (+1 pad col).
__global__ __launch_bounds__(256) void transpose_convert(
    const float* __restrict__ src, bf16_t* __restrict__ dst,
    int rows, int cols)
{
    __shared__ bf16_t t[64][65];
    const int tx = threadIdx.x & 63;
    const int ty = threadIdx.x >> 6;
    const int c0 = blockIdx.x * 64;
    const int r0 = blockIdx.y * 64;
#pragma unroll
    for (int r = ty; r < 64; r += 4)
        t[r][tx] = (bf16_t)src[(size_t)(r0 + r) * cols + c0 + tx];
    __syncthreads();
#pragma unroll
    for (int r = ty; r < 64; r += 4)
        dst[(size_t)(c0 + r) * rows + r0 + tx] = t[tx][r];
}

__global__ void concat_bias(const float* __restrict__ bq, const float* __restrict__ bk,
                            const float* __restrict__ bv, float* __restrict__ o) {
    int i = blockIdx.x * 256 + threadIdx.x;
    if (i >= 3072) return;
    o[i] = (i < 2048) ? bq[i] : (i < 2560 ? bk[i - 2048] : bv[i - 2560]);
}

// Per-token grouped attention (softmax over G=4 groups at same position), bf16 in/out.
// One block/token; wave w -> heads 4w..4w+3; lane holds elems 2*lane, 2*lane+1.
// Writes DIRECTLY to the compact [16384][2048] buffer (so=2048).
__global__ __launch_bounds__(256) void gqa_attn(
    const bf16_t* __restrict__ q, int sq,
    const bf16_t* __restrict__ kv, int skv,
    bf16_t* __restrict__ out, int so)
{
    const int token = blockIdx.x;
    const int wave = threadIdx.x >> 6, lane = threadIdx.x & 63;
    const bf16_t* qb  = q  + (size_t)token * sq;
    const bf16_t* kvb = kv + (size_t)token * skv;
    const float scale = 0.08838834764831845f;  // 1/sqrt(128)
    float k0[4], k1[4], v0[4], v1[4];
#pragma unroll
    for (int g = 0; g < 4; ++g) {
        uint32_t ku = *(const uint32_t*)(kvb + g * 128 + lane * 2);
        k0[g] = __uint_as_float(ku << 16);
        k1[g] = __uint_as_float(ku & 0xffff0000u);
        uint32_t vu = *(const uint32_t*)(kvb + 512 + g * 128 + lane * 2);
        v0[g] = __uint_as_float(vu << 16);
        v1[g] = __uint_as_float(vu & 0xffff0000u);
    }
#pragma unroll
    for (int hh = 0; hh < 4; ++hh) {
        const int h = wave * 4 + hh;
        uint32_t qu = *(const uint32_t*)(qb + h * 128 + lane * 2);
        float q0 = __uint_as_float(qu << 16);
        float q1 = __uint_as_float(qu & 0xffff0000u);
        float s[4];
#pragma unroll
        for (int g = 0; g < 4; ++g) s[g] = q0 * k0[g] + q1 * k1[g];
#pragma unroll
        for (int off = 32; off > 0; off >>= 1)
#pragma unroll
            for (int g = 0; g < 4; ++g) s[g] += __shfl_xor(s[g], off);
        float mx = fmaxf(fmaxf(s[0], s[1]), fmaxf(s[2], s[3]));
        float e[4], sum = 0.f;
#pragma unroll
        for (int g = 0; g < 4; ++g) { e[g] = __expf((s[g] - mx) * scale); sum += e[g]; }
        const float rs = 1.0f / sum;
        float o0 = 0.f, o1 = 0.f;
#pragma unroll
        for (int g = 0; g < 4; ++g) { o0 += e[g] * v0[g]; o1 += e[g] * v1[g]; }
        o0 *= rs; o1 *= rs;
        bf16_t* op = out + (size_t)token * so + h * 128 + lane * 2;
        op[0] = (bf16_t)o0;
        op[1] = (bf16_t)o1;
    }
}

extern "C" void kernel_launch(void* const* d_in, const int* in_sizes, int n_in,
                              void* d_out, int out_size, void* d_ws, size_t ws_size,
                              hipStream_t stream) {
    const float* hs = (const float*)d_in[0];
    const float* Wq = (const float*)d_in[1];
    const float* bq = (const float*)d_in[2];
    const float* Wk = (const float*)d_in[3];
    const float* bk = (const float*)d_in[4];
    const float* Wv = (const float*)d_in[5];
    const float* bv = (const float*)d_in[6];
    const float* Wo = (const float*)d_in[7];
    const float* bo = (const float*)d_in[8];
    float* outp = (float*)d_out;
    char* ws = (char*)d_ws;

    // ws layout (88.1 MB total):
    //   Wt   [3072][2048] bf16 : 0          .. 12,582,912
    //   Wot  [2048][2048] bf16 : 12,582,912 .. 20,971,520
    //   bqkv [3072]       f32  : 20,971,520 .. 20,983,808
    //   X    (67,108,864 B)    : 20,983,808 .. 88,092,672   (hs_bf16, then atto)
    bf16_t* Wt     = (bf16_t*)(ws);
    bf16_t* Wot    = (bf16_t*)(ws + 12582912);
    float*  bqkv   = (float*)(ws + 20971520);
    bf16_t* hs_b   = (bf16_t*)(ws + 20983808);
    bf16_t* atto   = (bf16_t*)(ws + 20983808);  // overlays hs_b (dead after QKV gemm)
    // qkv bf16 [16384][3072] = 100.7 MB lives in d_out (134.2 MB fp32) as scratch.
    bf16_t* qkv    = (bf16_t*)d_out;

    // Convert + transpose weights, concat biases, convert activations.
    f32_to_bf16<<<32768, 256, 0, stream>>>(hs, hs_b, 8388608);          // 16384*2048/4
    transpose_convert<<<dim3(32, 32), 256, 0, stream>>>(Wq, Wt, 2048, 2048);
    transpose_convert<<<dim3(8, 32), 256, 0, stream>>>(Wk, Wt + (size_t)2048 * 2048, 2048, 512);
    transpose_convert<<<dim3(8, 32), 256, 0, stream>>>(Wv, Wt + (size_t)2560 * 2048, 2048, 512);
    transpose_convert<<<dim3(32, 32), 256, 0, stream>>>(Wo, Wot, 2048, 2048);
    concat_bias<<<12, 256, 0, stream>>>(bq, bk, bv, bqkv);

    // QKV projection: [16384,2048] x [2048,3072] -> qkv (bf16, in d_out scratch)
    // grid = 64 Mtiles * 12 Ntiles = 768 (%8==0 -> simple XCD swizzle valid)
    gemm256<bf16_t><<<768, 512, 0, stream>>>(hs_b, 2048, Wt, 2048, bqkv, qkv, 3072, 2048, 12);
    // Grouped attention: read q/kv from qkv, write compact [16384][2048] to atto.
    gqa_attn<<<16384, 256, 0, stream>>>(qkv, 3072, qkv + 2048, 3072, atto, 2048);
    // Output projection -> fp32 d_out ; grid = 64 * 8 = 512 (%8==0)
    gemm256<float><<<512, 512, 0, stream>>>(atto, 2048, Wot, 2048, bo, outp, 2048, 2048, 8);
}

// Round 7
// 613.054 us; speedup vs baseline: 1.0446x; 1.0446x over previous
//
#include <hip/hip_runtime.h>
#include <hip/hip_bf16.h>
#include <stdint.h>

typedef __bf16 bf16_t;
typedef __bf16 bf16x8 __attribute__((ext_vector_type(8)));
typedef __bf16 bf16x4_t __attribute__((ext_vector_type(4)));
typedef float f32x4 __attribute__((ext_vector_type(4)));

#define AS1 __attribute__((address_space(1)))
#define AS3 __attribute__((address_space(3)))

__device__ __forceinline__ void stage16(const bf16_t* g, char* l) {
    __builtin_amdgcn_global_load_lds((const AS1 uint32_t*)g, (AS3 uint32_t*)l, 16, 0, 0);
}

#define BAR()   __builtin_amdgcn_s_barrier()
#define LGKM0() asm volatile("s_waitcnt lgkmcnt(0)" ::: "memory")
#define VMC(N)  asm volatile("s_waitcnt vmcnt(" #N ")" ::: "memory")
#define PRIO(p) __builtin_amdgcn_s_setprio(p)

// ----------------------------------------------------------------------------
// 256x256 SINGLE-BARRIER 8-phase bf16 GEMM (R5 version, best measured:
// 188-191 us QKV, MfmaUtil ~48.5%). R6's register read-ahead REGRESSED
// (VGPR spill: WRITE_SIZE +6MB) -> reverted exactly to this.
// See R3/R5 ledger comments: quadrant reads 12/4/4/4, stages P1/P2-P3/P5-P6/
// P7-P8, VMC(4)@P4+P8 certification, LGKM0 pre-barrier protocol.
// ----------------------------------------------------------------------------
template <typename OutT>
__global__ __launch_bounds__(512, 2) void gemm256(
    const bf16_t* __restrict__ A, int lda,
    const bf16_t* __restrict__ Bt, int ldb,
    const float* __restrict__ bias,
    OutT* __restrict__ C, int ldc,
    int K, int nTilesN)
{
    __shared__ char smem[131072];
    const int tid  = threadIdx.x;
    const int wave = tid >> 6;
    const int lane = tid & 63;
    const int wm = wave >> 2;   // 0..1 -> rows wm*128..+128
    const int wn = wave & 3;    // 0..3 -> cols wn*64..+64

    // XCD-aware bijective swizzle (gridDim.x % 8 == 0 guaranteed by caller)
    const int bid = blockIdx.x;
    const int swz = (bid & 7) * ((int)gridDim.x >> 3) + (bid >> 3);
    const int m0 = (swz / nTilesN) << 8;
    const int n0 = (swz % nTilesN) << 8;

    // Staging source: wave w, inst j covers subtile rg=w*2+j; lane's 16B chunk
    // col = (lane&3)*8, XOR 16 when subtile row (lane>>2) bit 3 set (inverse
    // st_16x32 pre-swizzle on the global source address).
    const int srow = lane >> 2;
    const int scol = ((lane & 3) * 8) ^ ((lane & 32) >> 1);
    const bf16_t* aS0 = A  + (size_t)(m0 + wave * 32 + srow) * lda + scol;
    const bf16_t* aS1 = aS0 + (size_t)16 * lda;
    const bf16_t* bS0 = Bt + (size_t)(n0 + wave * 32 + srow) * ldb + scol;
    const bf16_t* bS1 = bS0 + (size_t)16 * ldb;

    // LDS map: A(b,kk) = b*65536 + kk*16384 ; B(b,kk) = +32768.
#define STAGE_A(b,kk,kb) do { \
    stage16(aS0 + (kb) + (kk)*32, smem + (b)*65536 + (kk)*16384 + wave*2048); \
    stage16(aS1 + (kb) + (kk)*32, smem + (b)*65536 + (kk)*16384 + wave*2048 + 1024); } while(0)
#define STAGE_B(b,kk,kb) do { \
    stage16(bS0 + (kb) + (kk)*32, smem + (b)*65536 + 32768 + (kk)*16384 + wave*2048); \
    stage16(bS1 + (kb) + (kk)*32, smem + (b)*65536 + 32768 + (kk)*16384 + wave*2048 + 1024); } while(0)

    // ds_read: lane l -> row l&15, k-chunk (l>>4)*16B, with st_16x32 XOR.
    const int rdLane = (lane & 15) * 64 + (((lane >> 4) * 16) ^ ((lane & 8) << 2));
    const char* aRdB = smem + rdLane + wm * 8192;           // + mi*1024 + A(b,kk)
    const char* bRdB = smem + 32768 + rdLane + wn * 4096;   // + ni*1024 + base(b,kk)

    f32x4 acc[8][4];
#pragma unroll
    for (int i = 0; i < 8; ++i)
#pragma unroll
        for (int j = 0; j < 4; ++j) acc[i][j] = (f32x4){0.f, 0.f, 0.f, 0.f};
    bf16x8 bfr[2][4];   // [kk][ni]; held across the K-tile's 4 phases
    bf16x8 af[2][2];    // [t][kk], current mi-pair

#define RDB8(b) { _Pragma("unroll") \
    for (int kk = 0; kk < 2; ++kk) _Pragma("unroll") \
        for (int ni = 0; ni < 4; ++ni) \
            bfr[kk][ni] = *(const bf16x8*)(bRdB + (b)*65536 + kk*16384 + ni*1024); }
#define RDA(b,mp) { _Pragma("unroll") \
    for (int t = 0; t < 2; ++t) _Pragma("unroll") \
        for (int kk = 0; kk < 2; ++kk) \
            af[t][kk] = *(const bf16x8*)(aRdB + (b)*65536 + kk*16384 + ((mp)*2+t)*1024); }
#define MF(mp) { _Pragma("unroll") \
    for (int t = 0; t < 2; ++t) _Pragma("unroll") \
        for (int ni = 0; ni < 4; ++ni) _Pragma("unroll") \
            for (int kk = 0; kk < 2; ++kk) \
                acc[(mp)*2+t][ni] = __builtin_amdgcn_mfma_f32_16x16x32_bf16(af[t][kk], bfr[kk][ni], acc[(mp)*2+t][ni], 0, 0, 0); }
// Single-barrier phase: stage first (DMA starts earliest), then reads, then
// optional counted vmcnt, then drain reads PRE-barrier, barrier, MFMA.
#define PH(STG, RDS, WAIT, MFM) do { \
    STG; RDS; WAIT; LGKM0(); BAR(); PRIO(1); MFM; PRIO(0); } while(0)

    // Prologue: buf0 A+B @k=0, buf1-B @k=64 (12 loads); drain all; barrier.
    STAGE_A(0, 0, 0);  STAGE_A(0, 1, 0);  STAGE_B(0, 0, 0);  STAGE_B(0, 1, 0);
    STAGE_B(1, 0, 64); STAGE_B(1, 1, 64);
    VMC(0);
    BAR();

    const int NI = K >> 7;
    for (int it = 0; it < NI - 1; ++it) {
        const int kB  = (it << 7) + 64;    // this iter's buf1 (A deferred)
        const int kN0 = (it << 7) + 128;   // next buf0
        const int kN1 = (it << 7) + 192;   // next buf1
        PH(STAGE_A(1,0,kB); STAGE_A(1,1,kB), RDB8(0); RDA(0,0), , MF(0));
        PH(STAGE_B(0,0,kN0),                 RDA(0,1),          , MF(1));
        PH(STAGE_B(0,1,kN0),                 RDA(0,2),          , MF(2));
        PH(,                                 RDA(0,3),    VMC(4), MF(3));
        PH(STAGE_A(0,0,kN0),                 RDB8(1); RDA(1,0), , MF(0));
        PH(STAGE_A(0,1,kN0),                 RDA(1,1),          , MF(1));
        PH(STAGE_B(1,0,kN1),                 RDA(1,2),          , MF(2));
        PH(STAGE_B(1,1,kN1),                 RDA(1,3),    VMC(4), MF(3));
    }
    // Epilogue iteration: buf1-A still staged at P1; nothing else.
    {
        const int kB = ((NI - 1) << 7) + 64;
        PH(STAGE_A(1,0,kB); STAGE_A(1,1,kB), RDB8(0); RDA(0,0), , MF(0));
        PH(,                                 RDA(0,1),          , MF(1));
        PH(,                                 RDA(0,2),          , MF(2));
        PH(,                                 RDA(0,3),    VMC(0), MF(3));
        PH(,                                 RDB8(1); RDA(1,0), , MF(0));
        PH(,                                 RDA(1,1),          , MF(1));
        PH(,                                 RDA(1,2),          , MF(2));
        PH(,                                 RDA(1,3),          , MF(3));
    }
    BAR();

    // ---- Epilogue: LDS-staged coalesced C write (two 128-row halves) ----
    // Write-in swizzle: colb ^= quad*16*CSZ; readback applies same XOR.
    {
        const int mrow = lane & 15;
        const int quad = lane >> 4;
        constexpr int CSZ = (int)sizeof(OutT);
        float bias_v[4];
#pragma unroll
        for (int ni = 0; ni < 4; ++ni)
            bias_v[ni] = bias[n0 + wn * 64 + ni * 16 + mrow];
#pragma unroll
        for (int h = 0; h < 2; ++h) {
            if (wm == h) {
#pragma unroll
                for (int ni = 0; ni < 4; ++ni) {
                    const int colb = (wn * 64 + ni * 16 + mrow) * CSZ;
#pragma unroll
                    for (int mi = 0; mi < 8; ++mi)
#pragma unroll
                        for (int r = 0; r < 4; ++r) {
                            const int lrow = mi * 16 + quad * 4 + r;
                            *(OutT*)(smem + lrow * 256 * CSZ + (colb ^ (quad * 16 * CSZ))) =
                                (OutT)(acc[mi][ni][r] + bias_v[ni]);
                        }
                }
            }
            BAR();
            const int ROUNDS = 128 * 256 * CSZ / 8192;
#pragma unroll
            for (int rd = 0; rd < ROUNDS; ++rd) {
                const int flat = rd * 8192 + tid * 16;
                const int lrow = flat / (256 * CSZ);
                const int colb = flat % (256 * CSZ);
                const int q2 = (lrow >> 2) & 3;
                uint4 v = *(const uint4*)(smem + lrow * 256 * CSZ + (colb ^ (q2 * 16 * CSZ)));
                *(uint4*)((char*)C + ((size_t)(m0 + h * 128 + lrow) * ldc + n0) * CSZ + colb) = v;
            }
            BAR();
        }
    }
#undef STAGE_A
#undef STAGE_B
#undef RDB8
#undef RDA
#undef MF
#undef PH
}

// fp32 -> bf16 elementwise, 4 elems/thread.
__global__ __launch_bounds__(256) void f32_to_bf16(const float* __restrict__ src,
                                                   bf16_t* __restrict__ dst, int n4) {
    int i = blockIdx.x * 256 + threadIdx.x;
    if (i >= n4) return;
    float4 v = ((const float4*)src)[i];
    bf16x4_t o;
    o.x = (bf16_t)v.x; o.y = (bf16_t)v.y; o.z = (bf16_t)v.z; o.w = (bf16_t)v.w;
    ((bf16x4_t*)dst)[i] = o;
}

// dst[cols][rows] (bf16) = src[rows][cols]^T (fp32), 64x64 LDS tiles (+1 pad col).
__global__ __launch_bounds__(256) void transpose_convert(
    const float* __restrict__ src, bf16_t* __restrict__ dst,
    int rows, int cols)
{
    __shared__ bf16_t t[64][65];
    const int tx = threadIdx.x & 63;
    const int ty = threadIdx.x >> 6;
    const int c0 = blockIdx.x * 64;
    const int r0 = blockIdx.y * 64;
#pragma unroll
    for (int r = ty; r < 64; r += 4)
        t[r][tx] = (bf16_t)src[(size_t)(r0 + r) * cols + c0 + tx];
    __syncthreads();
#pragma unroll
    for (int r = ty; r < 64; r += 4)
        dst[(size_t)(c0 + r) * rows + r0 + tx] = t[tx][r];
}

__global__ void concat_bias(const float* __restrict__ bq, const float* __restrict__ bk,
                            const float* __restrict__ bv, float* __restrict__ o) {
    int i = blockIdx.x * 256 + threadIdx.x;
    if (i >= 3072) return;
    o[i] = (i < 2048) ? bq[i] : (i < 2560 ? bk[i - 2048] : bv[i - 2560]);
}

// ----------------------------------------------------------------------------
// Shuffle-free grouped attention: ONE THREAD per (token, head).
// R6 diagnosis: old kernel spent ~96 ds_bpermute (__shfl_xor) per thread on
// the 64-lane dot-product reduce -> LDS-crossbar-bound (~40-60+ us/CU floor).
// New: lane owns a full head; two passes over D=128 in 8-elem chunks; softmax
// over G=4 entirely in-lane. Zero cross-lane ops, zero LDS.
// Wave = 4 tokens x 16 heads (lane = tok4*16 + h). K/V loads are
// lane-broadcast within a token (L1 hits); q/o lines fully consumed across
// the chunk loop. Writes DIRECTLY to compact [16384][2048] out (so=2048).
// ----------------------------------------------------------------------------
__global__ __launch_bounds__(256) void gqa_attn(
    const bf16_t* __restrict__ qkv, int sq,
    bf16_t* __restrict__ out, int so)
{
    const int t = blockIdx.x * 256 + threadIdx.x;
    const int token = t >> 4;
    const int h = t & 15;
    const bf16_t* qb = qkv + (size_t)token * sq + h * 128;
    const bf16_t* kb = qkv + (size_t)token * sq + 2048;
    const bf16_t* vb = kb + 512;
    const float scale = 0.08838834764831845f;  // 1/sqrt(128)

    float s[4] = {0.f, 0.f, 0.f, 0.f};
#pragma unroll 4
    for (int c = 0; c < 16; ++c) {
        const uint4 qv = *(const uint4*)(qb + c * 8);
        const uint32_t qa[4] = {qv.x, qv.y, qv.z, qv.w};
#pragma unroll
        for (int g = 0; g < 4; ++g) {
            const uint4 kv4 = *(const uint4*)(kb + g * 128 + c * 8);
            const uint32_t ka[4] = {kv4.x, kv4.y, kv4.z, kv4.w};
#pragma unroll
            for (int w = 0; w < 4; ++w) {
                s[g] += __uint_as_float(qa[w] << 16) * __uint_as_float(ka[w] << 16);
                s[g] += __uint_as_float(qa[w] & 0xffff0000u) * __uint_as_float(ka[w] & 0xffff0000u);
            }
        }
    }
    const float mx = fmaxf(fmaxf(s[0], s[1]), fmaxf(s[2], s[3]));
    float p[4], sum = 0.f;
#pragma unroll
    for (int g = 0; g < 4; ++g) { p[g] = __expf((s[g] - mx) * scale); sum += p[g]; }
    const float rs = 1.0f / sum;
#pragma unroll
    for (int g = 0; g < 4; ++g) p[g] *= rs;

    bf16_t* ob = out + (size_t)token * so + h * 128;
#pragma unroll 4
    for (int c = 0; c < 16; ++c) {
        float o0[8] = {0.f, 0.f, 0.f, 0.f, 0.f, 0.f, 0.f, 0.f};
#pragma unroll
        for (int g = 0; g < 4; ++g) {
            const uint4 vv = *(const uint4*)(vb + g * 128 + c * 8);
            const uint32_t va[4] = {vv.x, vv.y, vv.z, vv.w};
#pragma unroll
            for (int w = 0; w < 4; ++w) {
                o0[w * 2]     += p[g] * __uint_as_float(va[w] << 16);
                o0[w * 2 + 1] += p[g] * __uint_as_float(va[w] & 0xffff0000u);
            }
        }
        bf16x8 ov;
#pragma unroll
        for (int j = 0; j < 8; ++j) ov[j] = (bf16_t)o0[j];
        *(bf16x8*)(ob + c * 8) = ov;
    }
}

extern "C" void kernel_launch(void* const* d_in, const int* in_sizes, int n_in,
                              void* d_out, int out_size, void* d_ws, size_t ws_size,
                              hipStream_t stream) {
    const float* hs = (const float*)d_in[0];
    const float* Wq = (const float*)d_in[1];
    const float* bq = (const float*)d_in[2];
    const float* Wk = (const float*)d_in[3];
    const float* bk = (const float*)d_in[4];
    const float* Wv = (const float*)d_in[5];
    const float* bv = (const float*)d_in[6];
    const float* Wo = (const float*)d_in[7];
    const float* bo = (const float*)d_in[8];
    float* outp = (float*)d_out;
    char* ws = (char*)d_ws;

    // ws layout (88.1 MB total):
    //   Wt   [3072][2048] bf16 : 0          .. 12,582,912
    //   Wot  [2048][2048] bf16 : 12,582,912 .. 20,971,520
    //   bqkv [3072]       f32  : 20,971,520 .. 20,983,808
    //   X    (67,108,864 B)    : 20,983,808 .. 88,092,672   (hs_bf16, then atto)
    bf16_t* Wt     = (bf16_t*)(ws);
    bf16_t* Wot    = (bf16_t*)(ws + 12582912);
    float*  bqkv   = (float*)(ws + 20971520);
    bf16_t* hs_b   = (bf16_t*)(ws + 20983808);
    bf16_t* atto   = (bf16_t*)(ws + 20983808);  // overlays hs_b (dead after QKV gemm)
    // qkv bf16 [16384][3072] = 100.7 MB lives in d_out (134.2 MB fp32) as scratch.
    bf16_t* qkv    = (bf16_t*)d_out;

    // Convert + transpose weights, concat biases, convert activations.
    f32_to_bf16<<<32768, 256, 0, stream>>>(hs, hs_b, 8388608);          // 16384*2048/4
    transpose_convert<<<dim3(32, 32), 256, 0, stream>>>(Wq, Wt, 2048, 2048);
    transpose_convert<<<dim3(8, 32), 256, 0, stream>>>(Wk, Wt + (size_t)2048 * 2048, 2048, 512);
    transpose_convert<<<dim3(8, 32), 256, 0, stream>>>(Wv, Wt + (size_t)2560 * 2048, 2048, 512);
    transpose_convert<<<dim3(32, 32), 256, 0, stream>>>(Wo, Wot, 2048, 2048);
    concat_bias<<<12, 256, 0, stream>>>(bq, bk, bv, bqkv);

    // QKV projection: [16384,2048] x [2048,3072] -> qkv (bf16, in d_out scratch)
    // grid = 64 Mtiles * 12 Ntiles = 768 (%8==0 -> simple XCD swizzle valid)
    gemm256<bf16_t><<<768, 512, 0, stream>>>(hs_b, 2048, Wt, 2048, bqkv, qkv, 3072, 2048, 12);
    // Grouped attention: 262144 threads = 1024 blocks; one thread per (token,head).
    gqa_attn<<<1024, 256, 0, stream>>>(qkv, 3072, atto, 2048);
    // Output projection -> fp32 d_out ; grid = 64 * 8 = 512 (%8==0)
    gemm256<float><<<512, 512, 0, stream>>>(atto, 2048, Wot, 2048, bo, outp, 2048, 2048, 8);
}

// Round 8
// 607.700 us; speedup vs baseline: 1.0538x; 1.0088x over previous
//
#include <hip/hip_runtime.h>
#include <hip/hip_bf16.h>
#include <stdint.h>

typedef __bf16 bf16_t;
typedef __bf16 bf16x8 __attribute__((ext_vector_type(8)));
typedef __bf16 bf16x4_t __attribute__((ext_vector_type(4)));
typedef float f32x4 __attribute__((ext_vector_type(4)));

#define AS1 __attribute__((address_space(1)))
#define AS3 __attribute__((address_space(3)))

__device__ __forceinline__ void stage16(const bf16_t* g, char* l) {
    __builtin_amdgcn_global_load_lds((const AS1 uint32_t*)g, (AS3 uint32_t*)l, 16, 0, 0);
}

#define BAR()   __builtin_amdgcn_s_barrier()
#define LGKM0() asm volatile("s_waitcnt lgkmcnt(0)" ::: "memory")
#define VMC(N)  asm volatile("s_waitcnt vmcnt(" #N ")" ::: "memory")
#define PRIO(p) __builtin_amdgcn_s_setprio(p)

// ----------------------------------------------------------------------------
// 256x256 SINGLE-BARRIER 8-phase bf16 GEMM (R5 version, best measured:
// 188-205 us QKV across runs, MfmaUtil 44-49%). R6's register read-ahead
// REGRESSED (VGPR spill); three schedule variants plateau here -> frozen.
// Ledger: quadrant reads 12/4/4/4; stages P1/P2-P3/P5-P6/P7-P8;
// VMC(4)@P4+P8 certification; LGKM0-pre-barrier protocol.
// ----------------------------------------------------------------------------
template <typename OutT>
__global__ __launch_bounds__(512, 2) void gemm256(
    const bf16_t* __restrict__ A, int lda,
    const bf16_t* __restrict__ Bt, int ldb,
    const float* __restrict__ bias,
    OutT* __restrict__ C, int ldc,
    int K, int nTilesN)
{
    __shared__ char smem[131072];
    const int tid  = threadIdx.x;
    const int wave = tid >> 6;
    const int lane = tid & 63;
    const int wm = wave >> 2;   // 0..1 -> rows wm*128..+128
    const int wn = wave & 3;    // 0..3 -> cols wn*64..+64

    // XCD-aware bijective swizzle (gridDim.x % 8 == 0 guaranteed by caller)
    const int bid = blockIdx.x;
    const int swz = (bid & 7) * ((int)gridDim.x >> 3) + (bid >> 3);
    const int m0 = (swz / nTilesN) << 8;
    const int n0 = (swz % nTilesN) << 8;

    // Staging source: wave w, inst j covers subtile rg=w*2+j; lane's 16B chunk
    // col = (lane&3)*8, XOR 16 when subtile row (lane>>2) bit 3 set (inverse
    // st_16x32 pre-swizzle on the global source address).
    const int srow = lane >> 2;
    const int scol = ((lane & 3) * 8) ^ ((lane & 32) >> 1);
    const bf16_t* aS0 = A  + (size_t)(m0 + wave * 32 + srow) * lda + scol;
    const bf16_t* aS1 = aS0 + (size_t)16 * lda;
    const bf16_t* bS0 = Bt + (size_t)(n0 + wave * 32 + srow) * ldb + scol;
    const bf16_t* bS1 = bS0 + (size_t)16 * ldb;

    // LDS map: A(b,kk) = b*65536 + kk*16384 ; B(b,kk) = +32768.
#define STAGE_A(b,kk,kb) do { \
    stage16(aS0 + (kb) + (kk)*32, smem + (b)*65536 + (kk)*16384 + wave*2048); \
    stage16(aS1 + (kb) + (kk)*32, smem + (b)*65536 + (kk)*16384 + wave*2048 + 1024); } while(0)
#define STAGE_B(b,kk,kb) do { \
    stage16(bS0 + (kb) + (kk)*32, smem + (b)*65536 + 32768 + (kk)*16384 + wave*2048); \
    stage16(bS1 + (kb) + (kk)*32, smem + (b)*65536 + 32768 + (kk)*16384 + wave*2048 + 1024); } while(0)

    // ds_read: lane l -> row l&15, k-chunk (l>>4)*16B, with st_16x32 XOR.
    const int rdLane = (lane & 15) * 64 + (((lane >> 4) * 16) ^ ((lane & 8) << 2));
    const char* aRdB = smem + rdLane + wm * 8192;           // + mi*1024 + A(b,kk)
    const char* bRdB = smem + 32768 + rdLane + wn * 4096;   // + ni*1024 + base(b,kk)

    f32x4 acc[8][4];
#pragma unroll
    for (int i = 0; i < 8; ++i)
#pragma unroll
        for (int j = 0; j < 4; ++j) acc[i][j] = (f32x4){0.f, 0.f, 0.f, 0.f};
    bf16x8 bfr[2][4];   // [kk][ni]; held across the K-tile's 4 phases
    bf16x8 af[2][2];    // [t][kk], current mi-pair

#define RDB8(b) { _Pragma("unroll") \
    for (int kk = 0; kk < 2; ++kk) _Pragma("unroll") \
        for (int ni = 0; ni < 4; ++ni) \
            bfr[kk][ni] = *(const bf16x8*)(bRdB + (b)*65536 + kk*16384 + ni*1024); }
#define RDA(b,mp) { _Pragma("unroll") \
    for (int t = 0; t < 2; ++t) _Pragma("unroll") \
        for (int kk = 0; kk < 2; ++kk) \
            af[t][kk] = *(const bf16x8*)(aRdB + (b)*65536 + kk*16384 + ((mp)*2+t)*1024); }
#define MF(mp) { _Pragma("unroll") \
    for (int t = 0; t < 2; ++t) _Pragma("unroll") \
        for (int ni = 0; ni < 4; ++ni) _Pragma("unroll") \
            for (int kk = 0; kk < 2; ++kk) \
                acc[(mp)*2+t][ni] = __builtin_amdgcn_mfma_f32_16x16x32_bf16(af[t][kk], bfr[kk][ni], acc[(mp)*2+t][ni], 0, 0, 0); }
// Single-barrier phase: stage first (DMA starts earliest), then reads, then
// optional counted vmcnt, then drain reads PRE-barrier, barrier, MFMA.
#define PH(STG, RDS, WAIT, MFM) do { \
    STG; RDS; WAIT; LGKM0(); BAR(); PRIO(1); MFM; PRIO(0); } while(0)

    // Prologue: buf0 A+B @k=0, buf1-B @k=64 (12 loads); drain all; barrier.
    STAGE_A(0, 0, 0);  STAGE_A(0, 1, 0);  STAGE_B(0, 0, 0);  STAGE_B(0, 1, 0);
    STAGE_B(1, 0, 64); STAGE_B(1, 1, 64);
    VMC(0);
    BAR();

    const int NI = K >> 7;
    for (int it = 0; it < NI - 1; ++it) {
        const int kB  = (it << 7) + 64;    // this iter's buf1 (A deferred)
        const int kN0 = (it << 7) + 128;   // next buf0
        const int kN1 = (it << 7) + 192;   // next buf1
        PH(STAGE_A(1,0,kB); STAGE_A(1,1,kB), RDB8(0); RDA(0,0), , MF(0));
        PH(STAGE_B(0,0,kN0),                 RDA(0,1),          , MF(1));
        PH(STAGE_B(0,1,kN0),                 RDA(0,2),          , MF(2));
        PH(,                                 RDA(0,3),    VMC(4), MF(3));
        PH(STAGE_A(0,0,kN0),                 RDB8(1); RDA(1,0), , MF(0));
        PH(STAGE_A(0,1,kN0),                 RDA(1,1),          , MF(1));
        PH(STAGE_B(1,0,kN1),                 RDA(1,2),          , MF(2));
        PH(STAGE_B(1,1,kN1),                 RDA(1,3),    VMC(4), MF(3));
    }
    // Epilogue iteration: buf1-A still staged at P1; nothing else.
    {
        const int kB = ((NI - 1) << 7) + 64;
        PH(STAGE_A(1,0,kB); STAGE_A(1,1,kB), RDB8(0); RDA(0,0), , MF(0));
        PH(,                                 RDA(0,1),          , MF(1));
        PH(,                                 RDA(0,2),          , MF(2));
        PH(,                                 RDA(0,3),    VMC(0), MF(3));
        PH(,                                 RDB8(1); RDA(1,0), , MF(0));
        PH(,                                 RDA(1,1),          , MF(1));
        PH(,                                 RDA(1,2),          , MF(2));
        PH(,                                 RDA(1,3),          , MF(3));
    }
    BAR();

    // ---- Epilogue: LDS-staged coalesced C write (two 128-row halves) ----
    // Write-in swizzle: colb ^= quad*16*CSZ; readback applies same XOR.
    {
        const int mrow = lane & 15;
        const int quad = lane >> 4;
        constexpr int CSZ = (int)sizeof(OutT);
        float bias_v[4];
#pragma unroll
        for (int ni = 0; ni < 4; ++ni)
            bias_v[ni] = bias[n0 + wn * 64 + ni * 16 + mrow];
#pragma unroll
        for (int h = 0; h < 2; ++h) {
            if (wm == h) {
#pragma unroll
                for (int ni = 0; ni < 4; ++ni) {
                    const int colb = (wn * 64 + ni * 16 + mrow) * CSZ;
#pragma unroll
                    for (int mi = 0; mi < 8; ++mi)
#pragma unroll
                        for (int r = 0; r < 4; ++r) {
                            const int lrow = mi * 16 + quad * 4 + r;
                            *(OutT*)(smem + lrow * 256 * CSZ + (colb ^ (quad * 16 * CSZ))) =
                                (OutT)(acc[mi][ni][r] + bias_v[ni]);
                        }
                }
            }
            BAR();
            const int ROUNDS = 128 * 256 * CSZ / 8192;
#pragma unroll
            for (int rd = 0; rd < ROUNDS; ++rd) {
                const int flat = rd * 8192 + tid * 16;
                const int lrow = flat / (256 * CSZ);
                const int colb = flat % (256 * CSZ);
                const int q2 = (lrow >> 2) & 3;
                uint4 v = *(const uint4*)(smem + lrow * 256 * CSZ + (colb ^ (q2 * 16 * CSZ)));
                *(uint4*)((char*)C + ((size_t)(m0 + h * 128 + lrow) * ldc + n0) * CSZ + colb) = v;
            }
            BAR();
        }
    }
#undef STAGE_A
#undef STAGE_B
#undef RDB8
#undef RDA
#undef MF
#undef PH
}

// ----------------------------------------------------------------------------
// Merged prep: ONE launch replaces 6 (f32->bf16 + 4 transposes + concat_bias).
// Block ranges:
//   [0,4096):    hs f32->bf16, grid-stride (8 float4/thread-iter x 8 iters)
//   [4096,5120): Wq transpose  (32x32 tiles)
//   [5120,5376): Wk transpose  (8x32)
//   [5376,5632): Wv transpose  (8x32)
//   [5632,6656): Wo transpose  (32x32)
//   [6656,6668): concat bias
// All regions independent; saves 5 launch gaps.
// ----------------------------------------------------------------------------
__global__ __launch_bounds__(256) void prep(
    const float* __restrict__ hs, bf16_t* __restrict__ hs_b,
    const float* __restrict__ Wq, const float* __restrict__ Wk,
    const float* __restrict__ Wv, const float* __restrict__ Wo,
    bf16_t* __restrict__ Wt, bf16_t* __restrict__ Wot,
    const float* __restrict__ bq, const float* __restrict__ bk,
    const float* __restrict__ bv, float* __restrict__ bqkv)
{
    __shared__ bf16_t t[64][65];
    const int b = blockIdx.x;
    if (b < 4096) {
        size_t i = (size_t)b * 256 + threadIdx.x;
#pragma unroll
        for (int r = 0; r < 8; ++r, i += 1048576) {
            float4 v = ((const float4*)hs)[i];
            bf16x4_t o;
            o.x = (bf16_t)v.x; o.y = (bf16_t)v.y; o.z = (bf16_t)v.z; o.w = (bf16_t)v.w;
            ((bf16x4_t*)hs_b)[i] = o;
        }
        return;
    }
    if (b >= 6656) {
        int i = (b - 6656) * 256 + threadIdx.x;
        if (i < 3072) bqkv[i] = (i < 2048) ? bq[i] : (i < 2560 ? bk[i - 2048] : bv[i - 2560]);
        return;
    }
    const float* src; bf16_t* dst; int cols, bx, by;
    if (b < 5120)      { src = Wq; dst = Wt;                     cols = 2048; int u = b - 4096; bx = u & 31; by = u >> 5; }
    else if (b < 5376) { src = Wk; dst = Wt + (size_t)2048*2048; cols = 512;  int u = b - 5120; bx = u & 7;  by = u >> 3; }
    else if (b < 5632) { src = Wv; dst = Wt + (size_t)2560*2048; cols = 512;  int u = b - 5376; bx = u & 7;  by = u >> 3; }
    else               { src = Wo; dst = Wot;                    cols = 2048; int u = b - 5632; bx = u & 31; by = u >> 5; }
    const int rows = 2048;
    const int tx = threadIdx.x & 63;
    const int ty = threadIdx.x >> 6;
    const int c0 = bx * 64;
    const int r0 = by * 64;
#pragma unroll
    for (int r = ty; r < 64; r += 4)
        t[r][tx] = (bf16_t)src[(size_t)(r0 + r) * cols + c0 + tx];
    __syncthreads();
#pragma unroll
    for (int r = ty; r < 64; r += 4)
        dst[(size_t)(c0 + r) * rows + r0 + tx] = t[tx][r];
}

// ----------------------------------------------------------------------------
// Shuffle-free grouped attention: ONE THREAD per (token, head). Zero cross-
// lane ops, zero LDS (R7, verified). Writes compact [16384][2048] (so=2048).
// ----------------------------------------------------------------------------
__global__ __launch_bounds__(256) void gqa_attn(
    const bf16_t* __restrict__ qkv, int sq,
    bf16_t* __restrict__ out, int so)
{
    const int t = blockIdx.x * 256 + threadIdx.x;
    const int token = t >> 4;
    const int h = t & 15;
    const bf16_t* qb = qkv + (size_t)token * sq + h * 128;
    const bf16_t* kb = qkv + (size_t)token * sq + 2048;
    const bf16_t* vb = kb + 512;
    const float scale = 0.08838834764831845f;  // 1/sqrt(128)

    float s[4] = {0.f, 0.f, 0.f, 0.f};
#pragma unroll 4
    for (int c = 0; c < 16; ++c) {
        const uint4 qv = *(const uint4*)(qb + c * 8);
        const uint32_t qa[4] = {qv.x, qv.y, qv.z, qv.w};
#pragma unroll
        for (int g = 0; g < 4; ++g) {
            const uint4 kv4 = *(const uint4*)(kb + g * 128 + c * 8);
            const uint32_t ka[4] = {kv4.x, kv4.y, kv4.z, kv4.w};
#pragma unroll
            for (int w = 0; w < 4; ++w) {
                s[g] += __uint_as_float(qa[w] << 16) * __uint_as_float(ka[w] << 16);
                s[g] += __uint_as_float(qa[w] & 0xffff0000u) * __uint_as_float(ka[w] & 0xffff0000u);
            }
        }
    }
    const float mx = fmaxf(fmaxf(s[0], s[1]), fmaxf(s[2], s[3]));
    float p[4], sum = 0.f;
#pragma unroll
    for (int g = 0; g < 4; ++g) { p[g] = __expf((s[g] - mx) * scale); sum += p[g]; }
    const float rs = 1.0f / sum;
#pragma unroll
    for (int g = 0; g < 4; ++g) p[g] *= rs;

    bf16_t* ob = out + (size_t)token * so + h * 128;
#pragma unroll 4
    for (int c = 0; c < 16; ++c) {
        float o0[8] = {0.f, 0.f, 0.f, 0.f, 0.f, 0.f, 0.f, 0.f};
#pragma unroll
        for (int g = 0; g < 4; ++g) {
            const uint4 vv = *(const uint4*)(vb + g * 128 + c * 8);
            const uint32_t va[4] = {vv.x, vv.y, vv.z, vv.w};
#pragma unroll
            for (int w = 0; w < 4; ++w) {
                o0[w * 2]     += p[g] * __uint_as_float(va[w] << 16);
                o0[w * 2 + 1] += p[g] * __uint_as_float(va[w] & 0xffff0000u);
            }
        }
        bf16x8 ov;
#pragma unroll
        for (int j = 0; j < 8; ++j) ov[j] = (bf16_t)o0[j];
        *(bf16x8*)(ob + c * 8) = ov;
    }
}

extern "C" void kernel_launch(void* const* d_in, const int* in_sizes, int n_in,
                              void* d_out, int out_size, void* d_ws, size_t ws_size,
                              hipStream_t stream) {
    const float* hs = (const float*)d_in[0];
    const float* Wq = (const float*)d_in[1];
    const float* bq = (const float*)d_in[2];
    const float* Wk = (const float*)d_in[3];
    const float* bk = (const float*)d_in[4];
    const float* Wv = (const float*)d_in[5];
    const float* bv = (const float*)d_in[6];
    const float* Wo = (const float*)d_in[7];
    const float* bo = (const float*)d_in[8];
    float* outp = (float*)d_out;
    char* ws = (char*)d_ws;

    // ws layout (88.1 MB total):
    //   Wt   [3072][2048] bf16 : 0          .. 12,582,912
    //   Wot  [2048][2048] bf16 : 12,582,912 .. 20,971,520
    //   bqkv [3072]       f32  : 20,971,520 .. 20,983,808
    //   X    (67,108,864 B)    : 20,983,808 .. 88,092,672   (hs_bf16, then atto)
    bf16_t* Wt     = (bf16_t*)(ws);
    bf16_t* Wot    = (bf16_t*)(ws + 12582912);
    float*  bqkv   = (float*)(ws + 20971520);
    bf16_t* hs_b   = (bf16_t*)(ws + 20983808);
    bf16_t* atto   = (bf16_t*)(ws + 20983808);  // overlays hs_b (dead after QKV gemm)
    // qkv bf16 [16384][3072] = 100.7 MB lives in d_out (134.2 MB fp32) as scratch.
    bf16_t* qkv    = (bf16_t*)d_out;

    // Merged prep: convert + 4 transposes + bias concat in ONE launch.
    prep<<<6668, 256, 0, stream>>>(hs, hs_b, Wq, Wk, Wv, Wo, Wt, Wot, bq, bk, bv, bqkv);

    // QKV projection: [16384,2048] x [2048,3072] -> qkv (bf16, in d_out scratch)
    // grid = 64 Mtiles * 12 Ntiles = 768 (%8==0 -> simple XCD swizzle valid)
    gemm256<bf16_t><<<768, 512, 0, stream>>>(hs_b, 2048, Wt, 2048, bqkv, qkv, 3072, 2048, 12);
    // Grouped attention: 262144 threads = 1024 blocks; one thread per (token,head).
    gqa_attn<<<1024, 256, 0, stream>>>(qkv, 3072, atto, 2048);
    // Output projection -> fp32 d_out ; grid = 64 * 8 = 512 (%8==0)
    gemm256<float><<<512, 512, 0, stream>>>(atto, 2048, Wot, 2048, bo, outp, 2048, 2048, 8);
}